// Round 13
// baseline (2657.477 us; speedup 1.0000x reference)
//
// RNN_79577154060490 — round 14: 2 blocks/CU (512 blocks, 64KB W-tile each) for
// TLP latency hiding of the rendezvous chain. Sync protocol = frozen r6 shape.
// h0=p0@W_enc^T; 100x h=tanh(v@W_ih^T+h@W_hh^T); out = g@W_dec^T + b
//
// Ledger: r6 sync = local optimum (r7/r9/r10 all regressed). r12: Part bf16 ->
// WRITE 10x down, loop unchanged => rendezvous-latency-bound (~9.2us/step,
// serial chain fully EXPOSED at 1 block/CU). r13: in-kernel W cvt, total 1054.
// Round-14 (one mechanism): occupancy 1->2 blocks/CU. W tile 128->64KB;
// block=(gt, ks2 0..15) owns k-slice ks2*256 (2 chunks). While one block spins
// at its LLC rendezvous, the co-resident block's mm/reduce keeps the CU busy
// (m114 co-scheduling). Flag agents stay per-block tid0/tid<3 (r7's per-wave
// multiplication NOT repeated); counts double to 16/step.
//   mm(gt,ks2): RAW hcnt[2ks2],hcnt[2ks2+1] >= 16t; WAR hcnt[gt] >= 16t.
//   Part [gt][ks2 16][128][128] bf16 (16MB; 2MB/XCD, L2-resident as r12).
//   reduce: 8 rows/block, 2 g/thread, 16-slice dword sc0 loads.
//   XCD map bijective: xcd=bid&7, gt=xcd*4+(bid>>7), ks2=(bid>>3)&15.
//
// ws layout (bytes) [WhS region fallback-only]:
//   [0,         33554432)   WhS  bf16 (fallback only)
//   [33554432,  37748736)   WdS  bf16 [pt4][chunk32][nt8][ktl4][64][8]
//   [37748736,  38797312)   H0S  bf16 A-image (1MB)
//   [38797312, 143654912)   Gsw  bf16 [t100] A-images (100MB)
//   [143654912,160432128)   Part region (main: bf16 [gt32][ks2 16][128][128])
//   [160432128,160440320)   flags int[2048] (pcnt[32] @0, hcnt[32] @+1024; stride 32)

#include <hip/hip_runtime.h>
#include <stdint.h>

namespace {
constexpr int kT = 100;
constexpr int kNG = 4096;
constexpr int kNP = 512;

__device__ __forceinline__ uint16_t f2bf(float f) {
  uint32_t u = __float_as_uint(f);
  u += 0x7FFFu + ((u >> 16) & 1u);
  return (uint16_t)(u >> 16);
}

__device__ __forceinline__ float bfbits(uint32_t lo16) {  // bf16 bits -> f32
  return __uint_as_float(lo16 << 16);
}

__device__ __forceinline__ float fast_tanh(float x) {
  float xc = fminf(fmaxf(x, -15.f), 15.f);
  float e = __expf(2.f * xc);
  return (e - 1.f) / (e + 1.f);
}

__device__ __forceinline__ void gl2lds16(const void* g, void* l) {
  __builtin_amdgcn_global_load_lds((const __attribute__((address_space(1))) unsigned int*)g,
                                   (__attribute__((address_space(3))) unsigned int*)l, 16, 0, 0);
}

// fragment-image element offsets (within one tensor)
__device__ __forceinline__ size_t a_img_off(int b, int g) {  // g = k index
  return ((size_t)(((g >> 7) * 8 + (b >> 4)) * 4 + ((g >> 5) & 3)) * 64 +
          ((g >> 3) & 3) * 16 + (b & 15)) * 8 + (g & 7);
}
}  // namespace

typedef short bf16x8 __attribute__((ext_vector_type(8)));
typedef float f32x4 __attribute__((ext_vector_type(4)));

// ---- (fallback only) cvt W_hh fp32 -> WhS B-image bf16, coalesced ----
__global__ __launch_bounds__(512) void cvt_whh_kernel(const float* __restrict__ W,
                                                      uint16_t* __restrict__ WhS) {
  const int u = blockIdx.x * 512 + threadIdx.x;  // 2M units of 8 elements
  const int col = u & 15, half = (u >> 4) & 3, ktl = (u >> 6) & 3;
  const int nt = (u >> 8) & 7, chunk = (u >> 11) & 31, gt = u >> 16;
  const int g = gt * 128 + nt * 16 + col;
  const int k0 = chunk * 128 + ktl * 32 + half * 8;
  const float4 x = *(const float4*)(W + (size_t)g * kNG + k0);
  const float4 y = *(const float4*)(W + (size_t)g * kNG + k0 + 4);
  uint4 o;
  o.x = (uint32_t)f2bf(x.x) | ((uint32_t)f2bf(x.y) << 16);
  o.y = (uint32_t)f2bf(x.z) | ((uint32_t)f2bf(x.w) << 16);
  o.z = (uint32_t)f2bf(y.x) | ((uint32_t)f2bf(y.y) << 16);
  o.w = (uint32_t)f2bf(y.z) | ((uint32_t)f2bf(y.w) << 16);
  *(uint4*)(WhS + (size_t)u * 8) = o;
}

// ---- cvt W_dec fp32 [512][4096] -> WdS B-image bf16 (coalesced) + flag zero ----
__global__ __launch_bounds__(512) void cvt_wdec_kernel(const float* __restrict__ W,
                                                       uint16_t* __restrict__ WdS,
                                                       int* __restrict__ flags) {
  if (blockIdx.x == 511) {
    for (int i = threadIdx.x; i < 2048; i += 512) flags[i] = 0;
  }
  const int u = blockIdx.x * 512 + threadIdx.x;  // 256K units
  const int col = u & 15, half = (u >> 4) & 3, ktl = (u >> 6) & 3;
  const int nt = (u >> 8) & 7, chunk = (u >> 11) & 31, pt = u >> 16;
  const int p = pt * 128 + nt * 16 + col;
  const int k0 = chunk * 128 + ktl * 32 + half * 8;
  const float4 x = *(const float4*)(W + (size_t)p * kNG + k0);
  const float4 y = *(const float4*)(W + (size_t)p * kNG + k0 + 4);
  uint4 o;
  o.x = (uint32_t)f2bf(x.x) | ((uint32_t)f2bf(x.y) << 16);
  o.y = (uint32_t)f2bf(x.z) | ((uint32_t)f2bf(x.w) << 16);
  o.z = (uint32_t)f2bf(y.x) | ((uint32_t)f2bf(y.y) << 16);
  o.w = (uint32_t)f2bf(y.z) | ((uint32_t)f2bf(y.w) << 16);
  *(uint4*)(WdS + (size_t)u * 8) = o;
}

// ---- encoder: H0S = A-image of p0 @ Wenc^T (bf16) ----
__global__ __launch_bounds__(512, 2) void enc_kernel(const float* __restrict__ p0,
                                                     const float* __restrict__ Wenc,
                                                     uint16_t* __restrict__ H0S) {
  __shared__ alignas(16) uint16_t Wlds[16 * 64 * 8];
  const int tid = threadIdx.x;
  const int g0 = blockIdx.x * 16;
  for (int f = tid; f < 16 * 64; f += 512) {
    const int kt = f >> 6, fl = f & 63;
    const int g = g0 + (fl & 15);
    const int k = kt * 32 + ((fl >> 4) << 3);
    const float* s = Wenc + (size_t)g * kNP + k;
    uint16_t* d = Wlds + f * 8;
#pragma unroll
    for (int j = 0; j < 8; j++) d[j] = f2bf(s[j]);
  }
  __syncthreads();
  const int wave = tid >> 6;
  const int lane = tid & 63;
  const int mrow = wave * 16 + (lane & 15);
  const float* arow = p0 + (size_t)mrow * kNP + ((lane >> 4) << 3);
  f32x4 acc = {0.f, 0.f, 0.f, 0.f};
#pragma unroll
  for (int kt = 0; kt < 16; kt++) {
    const float* ap = arow + kt * 32;
    bf16x8 a;
#pragma unroll
    for (int j = 0; j < 8; j++) a[j] = (short)f2bf(ap[j]);
    bf16x8 b = *(const bf16x8*)(Wlds + (kt * 64 + lane) * 8);
    acc = __builtin_amdgcn_mfma_f32_16x16x32_bf16(a, b, acc, 0, 0, 0);
  }
  const int gcol = g0 + (lane & 15);
  const int rbase = wave * 16 + ((lane >> 4) << 2);
#pragma unroll
  for (int r = 0; r < 4; r++) {
    H0S[a_img_off(rbase + r, gcol)] = f2bf(acc[r]);
  }
}

// ---- persistent RNN loop: 512 blocks, 2/CU; r6 sync shape; 64KB W tile ----
__global__ __launch_bounds__(512, 4) void rnn_loop_kernel(const float* __restrict__ Whh,
                                                          const uint16_t* __restrict__ H0S,
                                                          uint16_t* __restrict__ Gsw,
                                                          float* __restrict__ Part,
                                                          const float* __restrict__ v,
                                                          const float* __restrict__ Wih,
                                                          int* __restrict__ flags) {
  extern __shared__ uint16_t wlds[];  // 65536 B = 2 chunks x 16384 elems
  const int tid = threadIdx.x;
  const int wave = tid >> 6, lane = tid & 63;
  const int bid = blockIdx.x;
  const int xcd = bid & 7;                    // dispatch round-robin heuristic
  const int gt = xcd * 4 + (bid >> 7);        // all 16 ks2-blocks of gt on one XCD
  const int ks2 = (bid >> 3) & 15;
  const int mg = wave >> 1, ng = wave & 1;

  int* pcnt = flags;            // [gt] stride 32
  int* hcnt = flags + 32 * 32;  // [gt] stride 32
  uint16_t* PartB = (uint16_t*)Part;  // bf16 [gt32][ks2 16][128][128]

  // one-time: convert fp32 W slice (rows gt*128..+128, k ks2*256..+256) -> LDS
  {
    const float* wsrc = Whh + (size_t)(gt * 128) * kNG + ks2 * 256;
#pragma unroll
    for (int i = 0; i < 8; i++) {
      const int u = (i << 9) + tid;  // 0..4095 units of 8 floats
      const int g = u >> 5, ku = u & 31;
      const float* s = wsrc + (size_t)g * kNG + (ku << 3);
      const float4 x = *(const float4*)(s);
      const float4 y = *(const float4*)(s + 4);
      // chunk_local=ku>>4, ktl=(ku>>2)&3, half=ku&3, nt=g>>4, col=g&15
      const int lu = (((((ku >> 4) << 3) + (g >> 4)) << 2) + ((ku >> 2) & 3)) * 64 +
                     ((ku & 3) << 4) + (g & 15);
      bf16x8 o;
      o[0] = (short)f2bf(x.x); o[1] = (short)f2bf(x.y);
      o[2] = (short)f2bf(x.z); o[3] = (short)f2bf(x.w);
      o[4] = (short)f2bf(y.x); o[5] = (short)f2bf(y.y);
      o[6] = (short)f2bf(y.z); o[7] = (short)f2bf(y.w);
      *(bf16x8*)(wlds + ((size_t)lu << 3)) = o;
    }
  }
  __syncthreads();

  // reduce-phase coords: 8 rows x 128 g per block, 2 g per thread
  const int rbred = ks2 * 8 + (tid >> 6);  // batch row
  const int gl = (tid & 63) << 1;          // local g 0..126 (even)
  const int gg = gt * 128 + gl;            // global g
  uint16_t* myPart = PartB + (((size_t)(gt * 16 + ks2)) << 14);

  // loop-invariant Wih rows for this thread's 2 g
  const float4 w01 = *(const float4*)(Wih + gg * 2);  // {w[g].0, w[g].1, w[g+1].0, w[g+1].1}

  for (int t = 0; t < kT; t++) {
    // wait: RAW on h chunks 2ks2,2ks2+1 (gt'=chunk); WAR on hcnt[gt]
    if (t > 0) {
      const int target = 16 * t;
      if (tid < 3) {
        int* f = (tid < 2) ? (hcnt + ((ks2 * 2 + tid) << 5)) : (hcnt + (gt << 5));
        while (__hip_atomic_load(f, __ATOMIC_RELAXED, __HIP_MEMORY_SCOPE_AGENT) < target)
          __builtin_amdgcn_s_sleep(1);
      }
      __builtin_amdgcn_fence(__ATOMIC_ACQUIRE, "workgroup");  // compiler order; no cache op
      __syncthreads();
    }

    // prefetch v(t) for the reduce phase (latency hides under mm)
    const float v0 = v[(rbred * kT + t) * 2 + 0];
    const float v1 = v[(rbred * kT + t) * 2 + 1];

    const uint16_t* Aimg = (t == 0) ? H0S : (Gsw + (((size_t)(t - 1)) << 19));
    f32x4 acc[2][4];
#pragma unroll
    for (int i = 0; i < 2; i++)
#pragma unroll
      for (int j = 0; j < 4; j++) acc[i][j] = (f32x4){0.f, 0.f, 0.f, 0.f};

#pragma unroll
    for (int kc = 0; kc < 2; kc++) {
      const uint16_t* Ac = Aimg + ((size_t)(ks2 * 2 + kc) << 14);
      bf16x8 a[2][4];
#pragma unroll
      for (int mi = 0; mi < 2; mi++)
#pragma unroll
        for (int ktl = 0; ktl < 4; ktl++)
          a[mi][ktl] = *(const bf16x8*)(Ac + ((((mg * 2 + mi) * 4 + ktl) * 64 + lane) << 3));
#pragma unroll
      for (int ktl = 0; ktl < 4; ktl++) {
#pragma unroll
        for (int nt = 0; nt < 4; nt++) {
          bf16x8 b = *(const bf16x8*)(wlds + (kc << 14) +
                                      ((((ng * 4 + nt) * 4 + ktl) * 64 + lane) << 3));
          acc[0][nt] = __builtin_amdgcn_mfma_f32_16x16x32_bf16(a[0][ktl], b, acc[0][nt], 0, 0, 0);
          acc[1][nt] = __builtin_amdgcn_mfma_f32_16x16x32_bf16(a[1][ktl], b, acc[1][nt], 0, 0, 0);
        }
      }
    }
    // Part write: bf16 normal stores -> XCD-shared L2
    {
      const int gcol0 = (ng << 6);
      const int rbase = (mg << 5) + ((lane >> 4) << 2);
#pragma unroll
      for (int mi = 0; mi < 2; mi++)
#pragma unroll
        for (int nt = 0; nt < 4; nt++)
#pragma unroll
          for (int r = 0; r < 4; r++) {
            const int b = rbase + (mi << 4) + r;
            const int g = gcol0 + (nt << 4) + (lane & 15);
            myPart[(b << 7) + g] = f2bf(acc[mi][nt][r]);
          }
    }
    asm volatile("s_waitcnt vmcnt(0)" ::: "memory");  // Part committed
    __syncthreads();
    if (tid == 0) {
      // publish Part: RELAXED counter add (r6 shape; 16 producers per gt)
      __hip_atomic_fetch_add(pcnt + (gt << 5), 1, __ATOMIC_RELAXED, __HIP_MEMORY_SCOPE_AGENT);
      const int tgt = 16 * (t + 1);
      while (__hip_atomic_load(pcnt + (gt << 5), __ATOMIC_RELAXED, __HIP_MEMORY_SCOPE_AGENT) < tgt)
        __builtin_amdgcn_s_sleep(1);
      __builtin_amdgcn_fence(__ATOMIC_ACQUIRE, "workgroup");  // compiler order only
    }
    __syncthreads();

    // reduce rows [8*ks2..+8) over 16 slices + vin + tanh -> Gsw[t] A-image.
    // Part reads: sc0 dword (2 bf16 per slice per thread).
    {
      const uint16_t* pb = PartB + (((size_t)(gt * 16)) << 14) + (rbred << 7) + gl;
      uint32_t pv[16];
#pragma unroll
      for (int j = 0; j < 16; j++) {
        asm volatile("global_load_dword %0, %1, off sc0"
                     : "=v"(pv[j])
                     : "v"(pb + ((size_t)j << 14))
                     : "memory");
      }
      asm volatile("s_waitcnt vmcnt(0)" ::: "memory");
      __builtin_amdgcn_sched_barrier(0);  // rule #18: keep VALU below the waitcnt
      float s0 = 0.f, s1 = 0.f;
#pragma unroll
      for (int j = 0; j < 16; j++) {
        s0 += bfbits(pv[j] & 0xFFFFu);
        s1 += __uint_as_float(pv[j] & 0xFFFF0000u);
      }
      const uint16_t h0 = f2bf(fast_tanh(s0 + v0 * w01.x + v1 * w01.y));
      const uint16_t h1 = f2bf(fast_tanh(s1 + v0 * w01.z + v1 * w01.w));
      const uint32_t uval = (uint32_t)h0 | ((uint32_t)h1 << 16);
      uint16_t* Gt = Gsw + (((size_t)t) << 19);
      // h publish: atomic swap executes at the LLC (agent coherence point).
      // gl even => both bf16 land in one aligned dword of the A-image.
      __hip_atomic_exchange((uint32_t*)(Gt + a_img_off(rbred, gg)), uval,
                            __ATOMIC_RELAXED, __HIP_MEMORY_SCOPE_AGENT);
    }
    asm volatile("s_waitcnt vmcnt(0)" ::: "memory");  // h swaps done; Part consumed
    __syncthreads();
    if (tid == 0)
      __hip_atomic_fetch_add(hcnt + (gt << 5), 1, __ATOMIC_RELAXED, __HIP_MEMORY_SCOPE_AGENT);
  }
}

// ---- fallback step kernels (used only if cooperative launch is refused;
//      fp32 Part layout [ks8][128][4096] in the same ws region) ----
__global__ __launch_bounds__(512, 4) void stepmm_kernel(const uint16_t* __restrict__ Asrc,
                                                        const uint16_t* __restrict__ WhS,
                                                        float* __restrict__ Part) {
  __shared__ alignas(16) uint16_t lds[32768];
  const int tid = threadIdx.x;
  const int wave = tid >> 6, lane = tid & 63;
  const int gt = blockIdx.x >> 3, ks = blockIdx.x & 7;
  const int mg = wave >> 1, ng = wave & 1;
  const uint16_t* Wbase = WhS + ((size_t)gt << 19);
  f32x4 acc[2][4];
#pragma unroll
  for (int i = 0; i < 2; i++)
#pragma unroll
    for (int j = 0; j < 4; j++) acc[i][j] = (f32x4){0.f, 0.f, 0.f, 0.f};

  for (int kc = 0; kc < 4; kc++) {
    const int chunk = ks * 4 + kc;
    const uint16_t* Ac = Asrc + ((size_t)chunk << 14);
    const uint16_t* Bc = Wbase + ((size_t)chunk << 14);
#pragma unroll
    for (int i = 0; i < 8; i++) {
      const int j = wave * 8 + i;
      const uint16_t* s = (j < 32) ? (Ac + (j << 9)) : (Bc + ((j - 32) << 9));
      gl2lds16(s + (lane << 3), (void*)(lds + (j << 9)));
    }
    __syncthreads();
    const uint16_t* lA = lds;
    const uint16_t* lB = lds + 16384;
#pragma unroll
    for (int ktl = 0; ktl < 4; ktl++) {
      bf16x8 a0 = *(const bf16x8*)(lA + ((((mg * 2 + 0) * 4 + ktl) * 64 + lane) << 3));
      bf16x8 a1 = *(const bf16x8*)(lA + ((((mg * 2 + 1) * 4 + ktl) * 64 + lane) << 3));
#pragma unroll
      for (int nt = 0; nt < 4; nt++) {
        bf16x8 b = *(const bf16x8*)(lB + ((((ng * 4 + nt) * 4 + ktl) * 64 + lane) << 3));
        acc[0][nt] = __builtin_amdgcn_mfma_f32_16x16x32_bf16(a0, b, acc[0][nt], 0, 0, 0);
        acc[1][nt] = __builtin_amdgcn_mfma_f32_16x16x32_bf16(a1, b, acc[1][nt], 0, 0, 0);
      }
    }
    __syncthreads();
  }
  const int g0 = (gt << 7) + (ng << 6);
  const int rb = (mg << 5) + ((lane >> 4) << 2);
#pragma unroll
  for (int mi = 0; mi < 2; mi++)
#pragma unroll
    for (int nt = 0; nt < 4; nt++)
#pragma unroll
      for (int r = 0; r < 4; r++) {
        const int b = rb + (mi << 4) + r;
        const int g = g0 + (nt << 4) + (lane & 15);
        Part[(((size_t)(ks * 128 + b)) << 12) + g] = acc[mi][nt][r];
      }
}

__global__ __launch_bounds__(256) void steptanh_kernel(const float* __restrict__ Part,
                                                       const float* __restrict__ v,
                                                       const float* __restrict__ Wih,
                                                       uint16_t* __restrict__ Gt, int t) {
  const int tg = blockIdx.x * 256 + threadIdx.x;
  const int b = tg >> 9;
  const int g0 = (tg & 511) << 3;
  float s[8];
#pragma unroll
  for (int j = 0; j < 8; j++) s[j] = 0.f;
#pragma unroll
  for (int ks = 0; ks < 8; ks++) {
    const float4* p = (const float4*)(Part + (((size_t)(ks * 128 + b)) << 12) + g0);
    const float4 x = p[0], y = p[1];
    s[0] += x.x; s[1] += x.y; s[2] += x.z; s[3] += x.w;
    s[4] += y.x; s[5] += y.y; s[6] += y.z; s[7] += y.w;
  }
  const float v0 = v[(b * kT + t) * 2 + 0];
  const float v1 = v[(b * kT + t) * 2 + 1];
  uint16_t h[8];
#pragma unroll
  for (int j = 0; j < 8; j++) {
    const int g = g0 + j;
    const float pre = s[j] + v0 * Wih[g * 2 + 0] + v1 * Wih[g * 2 + 1];
    h[j] = f2bf(fast_tanh(pre));
  }
  uint4 u;
  u.x = (uint32_t)h[0] | ((uint32_t)h[1] << 16);
  u.y = (uint32_t)h[2] | ((uint32_t)h[3] << 16);
  u.z = (uint32_t)h[4] | ((uint32_t)h[5] << 16);
  u.w = (uint32_t)h[6] | ((uint32_t)h[7] << 16);
  const size_t off = ((size_t)(((g0 >> 7) * 8 + (b >> 4)) * 4 + ((g0 >> 5) & 3)) * 64 +
                      ((g0 >> 3) & 3) * 16 + (b & 15)) * 8;
  *(uint4*)(Gt + off) = u;
}

// ---- decoder: out[b,t,p] = Gsw[t] @ WdS[pt] + bias. XCD-swizzled grid ----
__global__ __launch_bounds__(512, 4) void dec_kernel(const uint16_t* __restrict__ Gsw,
                                                     const uint16_t* __restrict__ WdS,
                                                     const float* __restrict__ bd,
                                                     float* __restrict__ out) {
  __shared__ alignas(16) uint16_t lds[32768];
  const int slot = blockIdx.x & 7;
  const int m = blockIdx.x >> 3;
  const int t = slot + ((m >> 2) << 3);
  const int pt = m & 3;
  if (t >= kT) return;  // uniform per block; before any barrier
  const int tid = threadIdx.x;
  const int wave = tid >> 6, lane = tid & 63;
  const int mg = wave >> 1, ng = wave & 1;
  const uint16_t* Abase = Gsw + (size_t)t * 524288;
  const uint16_t* Bbase = WdS + (size_t)pt * 524288;
  f32x4 acc[2][4];
#pragma unroll
  for (int i = 0; i < 2; i++)
#pragma unroll
    for (int j = 0; j < 4; j++) acc[i][j] = (f32x4){0.f, 0.f, 0.f, 0.f};

  for (int chunk = 0; chunk < 32; chunk++) {
    const uint16_t* Ac = Abase + ((size_t)chunk << 14);
    const uint16_t* Bc = Bbase + ((size_t)chunk << 14);
#pragma unroll
    for (int i = 0; i < 8; i++) {
      const int j = wave * 8 + i;
      const uint16_t* s = (j < 32) ? (Ac + (j << 9)) : (Bc + ((j - 32) << 9));
      gl2lds16(s + (lane << 3), (void*)(lds + (j << 9)));
    }
    __syncthreads();
    const uint16_t* lA = lds;
    const uint16_t* lB = lds + 16384;
#pragma unroll
    for (int ktl = 0; ktl < 4; ktl++) {
      bf16x8 a0 = *(const bf16x8*)(lA + ((((mg * 2 + 0) * 4 + ktl) * 64 + lane) << 3));
      bf16x8 a1 = *(const bf16x8*)(lA + ((((mg * 2 + 1) * 4 + ktl) * 64 + lane) << 3));
#pragma unroll
      for (int nt = 0; nt < 4; nt++) {
        bf16x8 b = *(const bf16x8*)(lB + ((((ng * 4 + nt) * 4 + ktl) * 64 + lane) << 3));
        acc[0][nt] = __builtin_amdgcn_mfma_f32_16x16x32_bf16(a0, b, acc[0][nt], 0, 0, 0);
        acc[1][nt] = __builtin_amdgcn_mfma_f32_16x16x32_bf16(a1, b, acc[1][nt], 0, 0, 0);
      }
    }
    __syncthreads();
  }
  const int p0c = (pt << 7) + (ng << 6);
  const int rb = (mg << 5) + ((lane >> 4) << 2);
#pragma unroll
  for (int mi = 0; mi < 2; mi++)
#pragma unroll
    for (int nt = 0; nt < 4; nt++) {
      const int p = p0c + (nt << 4) + (lane & 15);
      const float bias = bd[p];
#pragma unroll
      for (int r = 0; r < 4; r++) {
        const int b = rb + (mi << 4) + r;
        out[((size_t)b * kT + t) * kNP + p] = acc[mi][nt][r] + bias;
      }
    }
}

extern "C" void kernel_launch(void* const* d_in, const int* in_sizes, int n_in,
                              void* d_out, int out_size, void* d_ws, size_t ws_size,
                              hipStream_t stream) {
  const float* v    = (const float*)d_in[0];
  const float* p0   = (const float*)d_in[1];
  const float* Wenc = (const float*)d_in[2];
  const float* Wih  = (const float*)d_in[3];
  const float* Whh  = (const float*)d_in[4];
  const float* Wdec = (const float*)d_in[5];
  const float* bdec = (const float*)d_in[6];
  float* out = (float*)d_out;

  uint8_t* ws = (uint8_t*)d_ws;
  uint16_t* WhS = (uint16_t*)(ws);                 // fallback only
  uint16_t* WdS = (uint16_t*)(ws + 33554432);
  uint16_t* H0S = (uint16_t*)(ws + 37748736);
  uint16_t* Gsw = (uint16_t*)(ws + 38797312);
  float*    Part = (float*)(ws + 143654912);
  int*      flags = (int*)(ws + 160432128);

  cvt_wdec_kernel<<<512, 512, 0, stream>>>(Wdec, WdS, flags);
  enc_kernel<<<256, 512, 0, stream>>>(p0, Wenc, H0S);

  // persistent flag-synced RNN loop: 512 blocks, 2/CU (64KB LDS each)
  const float* Whh_c = Whh;
  const uint16_t* H0S_c = H0S;
  void* args[7] = {(void*)&Whh_c, (void*)&H0S_c, (void*)&Gsw, (void*)&Part,
                   (void*)&v, (void*)&Wih, (void*)&flags};
  hipError_t e = hipLaunchCooperativeKernel(rnn_loop_kernel, dim3(512), dim3(512), args,
                                            (unsigned int)65536, stream);
  if (e != hipSuccess) {
    // fallback: per-step launches (round-1 path, ~1.96 ms class)
    (void)hipGetLastError();
    cvt_whh_kernel<<<4096, 512, 0, stream>>>(Whh, WhS);
    for (int t = 0; t < kT; t++) {
      const uint16_t* Asrc = (t == 0) ? H0S : (Gsw + (size_t)(t - 1) * 524288);
      stepmm_kernel<<<256, 512, 0, stream>>>(Asrc, WhS, Part);
      steptanh_kernel<<<256, 256, 0, stream>>>(Part, v, Wih, Gsw + (size_t)t * 524288, t);
    }
  }

  dec_kernel<<<416, 512, 0, stream>>>(Gsw, WdS, bdec, out);
}

// Round 14
// 1034.519 us; speedup vs baseline: 2.5688x; 2.5688x over previous
//
// RNN_79577154060490 — round 15: REVERT to round-13 verified optimum (1054us).
// h0=p0@W_enc^T; 100x h=tanh(v@W_ih^T+h@W_hh^T); out = g@W_dec^T + b
//
// Final ledger: r6 sync protocol = local optimum (r7 per-wave flags 3430us,
// r9 buffer_inv 1130us, r10 parallel stamps 1078us, all vs 947). r11 micro-opts
// -22us. r12 bf16 Part: WRITE 10x down (L2-resident), time ~flat => loop is
// RENDEZVOUS-LATENCY-bound (~9.2us/step; 2 LLC rendezvous + h publish serial
// chain), NOT BW/compute-bound (HBM 8%, MfmaUtil 20%). r13 in-kernel W cvt:
// total 1054 (best). r14 2-blocks/CU: REGRESSED 2.7x (16-way producer split
// destroyed Part L2-residency: WRITE 0.145->2.2GB; doubled RMW serialization).
// Five structural experiments against the r6 loop all regressed => this
// configuration is the structural floor for the persistent-RNN decomposition.
//
// ws layout (bytes) [WhS region fallback-only]:
//   [0,         33554432)   WhS  bf16 (fallback only)
//   [33554432,  37748736)   WdS  bf16 [pt4][chunk32][nt8][ktl4][64][8]
//   [37748736,  38797312)   H0S  bf16 A-image (1MB)
//   [38797312, 143654912)   Gsw  bf16 [t100] A-images (100MB)
//   [143654912,160432128)   Part region (main: bf16 [gt32][ks8][128][128])
//   [160432128,160440320)   flags int[2048] (pcnt[32] @0, hcnt[32] @+1024; stride 32)

#include <hip/hip_runtime.h>
#include <stdint.h>

namespace {
constexpr int kT = 100;
constexpr int kNG = 4096;
constexpr int kNP = 512;

__device__ __forceinline__ uint16_t f2bf(float f) {
  uint32_t u = __float_as_uint(f);
  u += 0x7FFFu + ((u >> 16) & 1u);
  return (uint16_t)(u >> 16);
}

__device__ __forceinline__ float bfbits(uint32_t lo16) {  // bf16 bits -> f32
  return __uint_as_float(lo16 << 16);
}

__device__ __forceinline__ float fast_tanh(float x) {
  float xc = fminf(fmaxf(x, -15.f), 15.f);
  float e = __expf(2.f * xc);
  return (e - 1.f) / (e + 1.f);
}

__device__ __forceinline__ void gl2lds16(const void* g, void* l) {
  __builtin_amdgcn_global_load_lds((const __attribute__((address_space(1))) unsigned int*)g,
                                   (__attribute__((address_space(3))) unsigned int*)l, 16, 0, 0);
}

// fragment-image element offsets (within one tensor)
__device__ __forceinline__ size_t a_img_off(int b, int g) {  // g = k index
  return ((size_t)(((g >> 7) * 8 + (b >> 4)) * 4 + ((g >> 5) & 3)) * 64 +
          ((g >> 3) & 3) * 16 + (b & 15)) * 8 + (g & 7);
}
}  // namespace

typedef short bf16x8 __attribute__((ext_vector_type(8)));
typedef float f32x4 __attribute__((ext_vector_type(4)));
typedef uint32_t u32x2 __attribute__((ext_vector_type(2)));

// ---- (fallback only) cvt W_hh fp32 -> WhS B-image bf16, coalesced ----
__global__ __launch_bounds__(512) void cvt_whh_kernel(const float* __restrict__ W,
                                                      uint16_t* __restrict__ WhS) {
  const int u = blockIdx.x * 512 + threadIdx.x;  // 2M units of 8 elements
  const int col = u & 15, half = (u >> 4) & 3, ktl = (u >> 6) & 3;
  const int nt = (u >> 8) & 7, chunk = (u >> 11) & 31, gt = u >> 16;
  const int g = gt * 128 + nt * 16 + col;
  const int k0 = chunk * 128 + ktl * 32 + half * 8;
  const float4 x = *(const float4*)(W + (size_t)g * kNG + k0);
  const float4 y = *(const float4*)(W + (size_t)g * kNG + k0 + 4);
  uint4 o;
  o.x = (uint32_t)f2bf(x.x) | ((uint32_t)f2bf(x.y) << 16);
  o.y = (uint32_t)f2bf(x.z) | ((uint32_t)f2bf(x.w) << 16);
  o.z = (uint32_t)f2bf(y.x) | ((uint32_t)f2bf(y.y) << 16);
  o.w = (uint32_t)f2bf(y.z) | ((uint32_t)f2bf(y.w) << 16);
  *(uint4*)(WhS + (size_t)u * 8) = o;  // fully linear store
}

// ---- cvt W_dec fp32 [512][4096] -> WdS B-image bf16 (coalesced) + flag zero ----
__global__ __launch_bounds__(512) void cvt_wdec_kernel(const float* __restrict__ W,
                                                       uint16_t* __restrict__ WdS,
                                                       int* __restrict__ flags) {
  if (blockIdx.x == 511) {
    for (int i = threadIdx.x; i < 2048; i += 512) flags[i] = 0;
  }
  const int u = blockIdx.x * 512 + threadIdx.x;  // 256K units
  const int col = u & 15, half = (u >> 4) & 3, ktl = (u >> 6) & 3;
  const int nt = (u >> 8) & 7, chunk = (u >> 11) & 31, pt = u >> 16;
  const int p = pt * 128 + nt * 16 + col;
  const int k0 = chunk * 128 + ktl * 32 + half * 8;
  const float4 x = *(const float4*)(W + (size_t)p * kNG + k0);
  const float4 y = *(const float4*)(W + (size_t)p * kNG + k0 + 4);
  uint4 o;
  o.x = (uint32_t)f2bf(x.x) | ((uint32_t)f2bf(x.y) << 16);
  o.y = (uint32_t)f2bf(x.z) | ((uint32_t)f2bf(x.w) << 16);
  o.z = (uint32_t)f2bf(y.x) | ((uint32_t)f2bf(y.y) << 16);
  o.w = (uint32_t)f2bf(y.z) | ((uint32_t)f2bf(y.w) << 16);
  *(uint4*)(WdS + (size_t)u * 8) = o;
}

// ---- encoder: H0S = A-image of p0 @ Wenc^T (bf16) ----
__global__ __launch_bounds__(512, 2) void enc_kernel(const float* __restrict__ p0,
                                                     const float* __restrict__ Wenc,
                                                     uint16_t* __restrict__ H0S) {
  __shared__ alignas(16) uint16_t Wlds[16 * 64 * 8];
  const int tid = threadIdx.x;
  const int g0 = blockIdx.x * 16;
  for (int f = tid; f < 16 * 64; f += 512) {
    const int kt = f >> 6, fl = f & 63;
    const int g = g0 + (fl & 15);
    const int k = kt * 32 + ((fl >> 4) << 3);
    const float* s = Wenc + (size_t)g * kNP + k;
    uint16_t* d = Wlds + f * 8;
#pragma unroll
    for (int j = 0; j < 8; j++) d[j] = f2bf(s[j]);
  }
  __syncthreads();
  const int wave = tid >> 6;
  const int lane = tid & 63;
  const int mrow = wave * 16 + (lane & 15);
  const float* arow = p0 + (size_t)mrow * kNP + ((lane >> 4) << 3);
  f32x4 acc = {0.f, 0.f, 0.f, 0.f};
#pragma unroll
  for (int kt = 0; kt < 16; kt++) {
    const float* ap = arow + kt * 32;
    bf16x8 a;
#pragma unroll
    for (int j = 0; j < 8; j++) a[j] = (short)f2bf(ap[j]);
    bf16x8 b = *(const bf16x8*)(Wlds + (kt * 64 + lane) * 8);
    acc = __builtin_amdgcn_mfma_f32_16x16x32_bf16(a, b, acc, 0, 0, 0);
  }
  const int gcol = g0 + (lane & 15);
  const int rbase = wave * 16 + ((lane >> 4) << 2);
#pragma unroll
  for (int r = 0; r < 4; r++) {
    H0S[a_img_off(rbase + r, gcol)] = f2bf(acc[r]);
  }
}

// ---- persistent RNN loop: round-6 protocol (frozen); W converted in-kernel ----
__global__ __launch_bounds__(512, 2) void rnn_loop_kernel(const float* __restrict__ Whh,
                                                          const uint16_t* __restrict__ H0S,
                                                          uint16_t* __restrict__ Gsw,
                                                          float* __restrict__ Part,
                                                          const float* __restrict__ v,
                                                          const float* __restrict__ Wih,
                                                          int* __restrict__ flags) {
  extern __shared__ uint16_t wlds[];  // 131072 B
  const int tid = threadIdx.x;
  const int wave = tid >> 6, lane = tid & 63;
  const int bid = blockIdx.x;
  const int xcd = bid & 7;                 // dispatch round-robin heuristic (perf-only)
  const int gt = xcd * 4 + (bid >> 6);     // all 8 ks-blocks of gt on one XCD
  const int ks = (bid >> 3) & 7;
  const int mg = wave >> 1, ng = wave & 1;

  int* pcnt = flags;            // [gt] stride 32
  int* hcnt = flags + 32 * 32;  // [gt] stride 32
  uint16_t* PartB = (uint16_t*)Part;  // bf16 [gt32][ks8][128][128]

  // one-time: convert this block's fp32 W slice (rows gt*128..+128, k
  // ks*512..+512) directly into the LDS B-image. Wave reads 2KB contiguous.
  {
    const float* wsrc = Whh + (size_t)(gt * 128) * kNG + ks * 512;
#pragma unroll
    for (int i = 0; i < 16; i++) {
      const int u = (i << 9) + tid;  // 0..8191 units of 8 floats
      const int g = u >> 6, ku = u & 63;
      const float* s = wsrc + (size_t)g * kNG + (ku << 3);
      const float4 x = *(const float4*)(s);
      const float4 y = *(const float4*)(s + 4);
      // chunk_local=ku>>4, ktl=(ku>>2)&3, half=ku&3, nt=g>>4, col=g&15
      const int lu = (((((ku >> 4) << 3) + (g >> 4)) << 2) + ((ku >> 2) & 3)) * 64 +
                     ((ku & 3) << 4) + (g & 15);
      bf16x8 o;
      o[0] = (short)f2bf(x.x); o[1] = (short)f2bf(x.y);
      o[2] = (short)f2bf(x.z); o[3] = (short)f2bf(x.w);
      o[4] = (short)f2bf(y.x); o[5] = (short)f2bf(y.y);
      o[6] = (short)f2bf(y.z); o[7] = (short)f2bf(y.w);
      *(bf16x8*)(wlds + ((size_t)lu << 3)) = o;
    }
  }
  __syncthreads();

  // reduce-phase coords: 16 rows x 128 g per block, 4 g per thread
  const int rbred = ks * 16 + (tid >> 5);  // batch row
  const int gl = (tid & 31) << 2;          // local g 0..124
  const int gg = gt * 128 + gl;            // global g
  uint16_t* myPart = PartB + (((size_t)(gt * 8 + ks)) << 14);

  // loop-invariant Wih rows for this thread's 4 g
  const float4 w0 = *(const float4*)(Wih + gg * 2);
  const float4 w1 = *(const float4*)(Wih + gg * 2 + 4);

  for (int t = 0; t < kT; t++) {
    // wait: h(t-1) chunks 4ks..4ks+3 ready; hcnt[gt] doubles as Part WAR gate
    if (t > 0) {
      const int target = 8 * t;
      if (tid < 5) {
        int* f = (tid < 4) ? (hcnt + ((ks * 4 + tid) << 5)) : (hcnt + (gt << 5));
        while (__hip_atomic_load(f, __ATOMIC_RELAXED, __HIP_MEMORY_SCOPE_AGENT) < target)
          __builtin_amdgcn_s_sleep(1);
      }
      __builtin_amdgcn_fence(__ATOMIC_ACQUIRE, "workgroup");  // compiler order; no cache op
      __syncthreads();
    }

    // prefetch v(t) for the reduce phase (latency hides under mm)
    const float v0 = v[(rbred * kT + t) * 2 + 0];
    const float v1 = v[(rbred * kT + t) * 2 + 1];

    const uint16_t* Aimg = (t == 0) ? H0S : (Gsw + (((size_t)(t - 1)) << 19));
    f32x4 acc[2][4];
#pragma unroll
    for (int i = 0; i < 2; i++)
#pragma unroll
      for (int j = 0; j < 4; j++) acc[i][j] = (f32x4){0.f, 0.f, 0.f, 0.f};

#pragma unroll
    for (int kc = 0; kc < 4; kc++) {
      const uint16_t* Ac = Aimg + ((size_t)(ks * 4 + kc) << 14);
      bf16x8 a[2][4];
#pragma unroll
      for (int mi = 0; mi < 2; mi++)
#pragma unroll
        for (int ktl = 0; ktl < 4; ktl++)
          a[mi][ktl] = *(const bf16x8*)(Ac + ((((mg * 2 + mi) * 4 + ktl) * 64 + lane) << 3));
#pragma unroll
      for (int ktl = 0; ktl < 4; ktl++) {
#pragma unroll
        for (int nt = 0; nt < 4; nt++) {
          bf16x8 b = *(const bf16x8*)(wlds + (kc << 14) +
                                      ((((ng * 4 + nt) * 4 + ktl) * 64 + lane) << 3));
          acc[0][nt] = __builtin_amdgcn_mfma_f32_16x16x32_bf16(a[0][ktl], b, acc[0][nt], 0, 0, 0);
          acc[1][nt] = __builtin_amdgcn_mfma_f32_16x16x32_bf16(a[1][ktl], b, acc[1][nt], 0, 0, 0);
        }
      }
    }
    // Part write: bf16 normal stores -> XCD-shared L2 (L2-resident, r12)
    {
      const int gcol0 = (ng << 6);
      const int rbase = (mg << 5) + ((lane >> 4) << 2);
#pragma unroll
      for (int mi = 0; mi < 2; mi++)
#pragma unroll
        for (int nt = 0; nt < 4; nt++)
#pragma unroll
          for (int r = 0; r < 4; r++) {
            const int b = rbase + (mi << 4) + r;
            const int g = gcol0 + (nt << 4) + (lane & 15);
            myPart[(b << 7) + g] = f2bf(acc[mi][nt][r]);
          }
    }
    asm volatile("s_waitcnt vmcnt(0)" ::: "memory");  // Part committed
    __syncthreads();
    if (tid == 0) {
      // publish Part: RELAXED counter add (round-6 verified local optimum)
      __hip_atomic_fetch_add(pcnt + (gt << 5), 1, __ATOMIC_RELAXED, __HIP_MEMORY_SCOPE_AGENT);
      const int tgt = 8 * (t + 1);
      while (__hip_atomic_load(pcnt + (gt << 5), __ATOMIC_RELAXED, __HIP_MEMORY_SCOPE_AGENT) < tgt)
        __builtin_amdgcn_s_sleep(1);
      __builtin_amdgcn_fence(__ATOMIC_ACQUIRE, "workgroup");  // compiler order only
    }
    __syncthreads();

    // reduce rows [16ks..+16) over 8 slices + vin + tanh -> Gsw[t] A-image.
    // Part reads: sc0 dwordx2 (4 bf16 per slice per thread).
    {
      const uint16_t* pb = PartB + (((size_t)(gt * 8)) << 14) + (rbred << 7) + gl;
      u32x2 pv[8];
#pragma unroll
      for (int j = 0; j < 8; j++) {
        asm volatile("global_load_dwordx2 %0, %1, off sc0"
                     : "=v"(pv[j])
                     : "v"(pb + ((size_t)j << 14))
                     : "memory");
      }
      asm volatile("s_waitcnt vmcnt(0)" ::: "memory");
      __builtin_amdgcn_sched_barrier(0);  // rule #18: keep VALU below the waitcnt
      float s0 = 0.f, s1 = 0.f, s2 = 0.f, s3 = 0.f;
#pragma unroll
      for (int j = 0; j < 8; j++) {
        s0 += bfbits(pv[j][0] & 0xFFFFu);
        s1 += __uint_as_float(pv[j][0] & 0xFFFF0000u);
        s2 += bfbits(pv[j][1] & 0xFFFFu);
        s3 += __uint_as_float(pv[j][1] & 0xFFFF0000u);
      }
      const uint16_t h0 = f2bf(fast_tanh(s0 + v0 * w0.x + v1 * w0.y));
      const uint16_t h1 = f2bf(fast_tanh(s1 + v0 * w0.z + v1 * w0.w));
      const uint16_t h2 = f2bf(fast_tanh(s2 + v0 * w1.x + v1 * w1.y));
      const uint16_t h3 = f2bf(fast_tanh(s3 + v0 * w1.z + v1 * w1.w));
      const uint32_t lo = (uint32_t)h0 | ((uint32_t)h1 << 16);
      const uint32_t hi = (uint32_t)h2 | ((uint32_t)h3 << 16);
      const unsigned long long uval = ((unsigned long long)hi << 32) | lo;
      uint16_t* Gt = Gsw + (((size_t)t) << 19);
      // h publish: atomic swap executes at the LLC (agent coherence point)
      __hip_atomic_exchange((unsigned long long*)(Gt + a_img_off(rbred, gg)), uval,
                            __ATOMIC_RELAXED, __HIP_MEMORY_SCOPE_AGENT);
    }
    asm volatile("s_waitcnt vmcnt(0)" ::: "memory");  // h swaps done; Part consumed
    __syncthreads();
    if (tid == 0)
      __hip_atomic_fetch_add(hcnt + (gt << 5), 1, __ATOMIC_RELAXED, __HIP_MEMORY_SCOPE_AGENT);
  }
}

// ---- fallback step kernels (used only if cooperative launch is refused;
//      fp32 Part layout [ks8][128][4096] in the same ws region) ----
__global__ __launch_bounds__(512, 4) void stepmm_kernel(const uint16_t* __restrict__ Asrc,
                                                        const uint16_t* __restrict__ WhS,
                                                        float* __restrict__ Part) {
  __shared__ alignas(16) uint16_t lds[32768];
  const int tid = threadIdx.x;
  const int wave = tid >> 6, lane = tid & 63;
  const int gt = blockIdx.x >> 3, ks = blockIdx.x & 7;
  const int mg = wave >> 1, ng = wave & 1;
  const uint16_t* Wbase = WhS + ((size_t)gt << 19);
  f32x4 acc[2][4];
#pragma unroll
  for (int i = 0; i < 2; i++)
#pragma unroll
    for (int j = 0; j < 4; j++) acc[i][j] = (f32x4){0.f, 0.f, 0.f, 0.f};

  for (int kc = 0; kc < 4; kc++) {
    const int chunk = ks * 4 + kc;
    const uint16_t* Ac = Asrc + ((size_t)chunk << 14);
    const uint16_t* Bc = Wbase + ((size_t)chunk << 14);
#pragma unroll
    for (int i = 0; i < 8; i++) {
      const int j = wave * 8 + i;
      const uint16_t* s = (j < 32) ? (Ac + (j << 9)) : (Bc + ((j - 32) << 9));
      gl2lds16(s + (lane << 3), (void*)(lds + (j << 9)));
    }
    __syncthreads();
    const uint16_t* lA = lds;
    const uint16_t* lB = lds + 16384;
#pragma unroll
    for (int ktl = 0; ktl < 4; ktl++) {
      bf16x8 a0 = *(const bf16x8*)(lA + ((((mg * 2 + 0) * 4 + ktl) * 64 + lane) << 3));
      bf16x8 a1 = *(const bf16x8*)(lA + ((((mg * 2 + 1) * 4 + ktl) * 64 + lane) << 3));
#pragma unroll
      for (int nt = 0; nt < 4; nt++) {
        bf16x8 b = *(const bf16x8*)(lB + ((((ng * 4 + nt) * 4 + ktl) * 64 + lane) << 3));
        acc[0][nt] = __builtin_amdgcn_mfma_f32_16x16x32_bf16(a0, b, acc[0][nt], 0, 0, 0);
        acc[1][nt] = __builtin_amdgcn_mfma_f32_16x16x32_bf16(a1, b, acc[1][nt], 0, 0, 0);
      }
    }
    __syncthreads();
  }
  const int g0 = (gt << 7) + (ng << 6);
  const int rb = (mg << 5) + ((lane >> 4) << 2);
#pragma unroll
  for (int mi = 0; mi < 2; mi++)
#pragma unroll
    for (int nt = 0; nt < 4; nt++)
#pragma unroll
      for (int r = 0; r < 4; r++) {
        const int b = rb + (mi << 4) + r;
        const int g = g0 + (nt << 4) + (lane & 15);
        Part[(((size_t)(ks * 128 + b)) << 12) + g] = acc[mi][nt][r];
      }
}

__global__ __launch_bounds__(256) void steptanh_kernel(const float* __restrict__ Part,
                                                       const float* __restrict__ v,
                                                       const float* __restrict__ Wih,
                                                       uint16_t* __restrict__ Gt, int t) {
  const int tg = blockIdx.x * 256 + threadIdx.x;
  const int b = tg >> 9;
  const int g0 = (tg & 511) << 3;
  float s[8];
#pragma unroll
  for (int j = 0; j < 8; j++) s[j] = 0.f;
#pragma unroll
  for (int ks = 0; ks < 8; ks++) {
    const float4* p = (const float4*)(Part + (((size_t)(ks * 128 + b)) << 12) + g0);
    const float4 x = p[0], y = p[1];
    s[0] += x.x; s[1] += x.y; s[2] += x.z; s[3] += x.w;
    s[4] += y.x; s[5] += y.y; s[6] += y.z; s[7] += y.w;
  }
  const float v0 = v[(b * kT + t) * 2 + 0];
  const float v1 = v[(b * kT + t) * 2 + 1];
  uint16_t h[8];
#pragma unroll
  for (int j = 0; j < 8; j++) {
    const int g = g0 + j;
    const float pre = s[j] + v0 * Wih[g * 2 + 0] + v1 * Wih[g * 2 + 1];
    h[j] = f2bf(fast_tanh(pre));
  }
  uint4 u;
  u.x = (uint32_t)h[0] | ((uint32_t)h[1] << 16);
  u.y = (uint32_t)h[2] | ((uint32_t)h[3] << 16);
  u.z = (uint32_t)h[4] | ((uint32_t)h[5] << 16);
  u.w = (uint32_t)h[6] | ((uint32_t)h[7] << 16);
  const size_t off = ((size_t)(((g0 >> 7) * 8 + (b >> 4)) * 4 + ((g0 >> 5) & 3)) * 64 +
                      ((g0 >> 3) & 3) * 16 + (b & 15)) * 8;
  *(uint4*)(Gt + off) = u;
}

// ---- decoder: out[b,t,p] = Gsw[t] @ WdS[pt] + bias. XCD-swizzled grid ----
__global__ __launch_bounds__(512, 4) void dec_kernel(const uint16_t* __restrict__ Gsw,
                                                     const uint16_t* __restrict__ WdS,
                                                     const float* __restrict__ bd,
                                                     float* __restrict__ out) {
  __shared__ alignas(16) uint16_t lds[32768];
  const int slot = blockIdx.x & 7;
  const int m = blockIdx.x >> 3;
  const int t = slot + ((m >> 2) << 3);
  const int pt = m & 3;
  if (t >= kT) return;  // uniform per block; before any barrier
  const int tid = threadIdx.x;
  const int wave = tid >> 6, lane = tid & 63;
  const int mg = wave >> 1, ng = wave & 1;
  const uint16_t* Abase = Gsw + (size_t)t * 524288;
  const uint16_t* Bbase = WdS + (size_t)pt * 524288;
  f32x4 acc[2][4];
#pragma unroll
  for (int i = 0; i < 2; i++)
#pragma unroll
    for (int j = 0; j < 4; j++) acc[i][j] = (f32x4){0.f, 0.f, 0.f, 0.f};

  for (int chunk = 0; chunk < 32; chunk++) {
    const uint16_t* Ac = Abase + ((size_t)chunk << 14);
    const uint16_t* Bc = Bbase + ((size_t)chunk << 14);
#pragma unroll
    for (int i = 0; i < 8; i++) {
      const int j = wave * 8 + i;
      const uint16_t* s = (j < 32) ? (Ac + (j << 9)) : (Bc + ((j - 32) << 9));
      gl2lds16(s + (lane << 3), (void*)(lds + (j << 9)));
    }
    __syncthreads();
    const uint16_t* lA = lds;
    const uint16_t* lB = lds + 16384;
#pragma unroll
    for (int ktl = 0; ktl < 4; ktl++) {
      bf16x8 a0 = *(const bf16x8*)(lA + ((((mg * 2 + 0) * 4 + ktl) * 64 + lane) << 3));
      bf16x8 a1 = *(const bf16x8*)(lA + ((((mg * 2 + 1) * 4 + ktl) * 64 + lane) << 3));
#pragma unroll
      for (int nt = 0; nt < 4; nt++) {
        bf16x8 b = *(const bf16x8*)(lB + ((((ng * 4 + nt) * 4 + ktl) * 64 + lane) << 3));
        acc[0][nt] = __builtin_amdgcn_mfma_f32_16x16x32_bf16(a0, b, acc[0][nt], 0, 0, 0);
        acc[1][nt] = __builtin_amdgcn_mfma_f32_16x16x32_bf16(a1, b, acc[1][nt], 0, 0, 0);
      }
    }
    __syncthreads();
  }
  const int p0c = (pt << 7) + (ng << 6);
  const int rb = (mg << 5) + ((lane >> 4) << 2);
#pragma unroll
  for (int mi = 0; mi < 2; mi++)
#pragma unroll
    for (int nt = 0; nt < 4; nt++) {
      const int p = p0c + (nt << 4) + (lane & 15);
      const float bias = bd[p];
#pragma unroll
      for (int r = 0; r < 4; r++) {
        const int b = rb + (mi << 4) + r;
        out[((size_t)b * kT + t) * kNP + p] = acc[mi][nt][r] + bias;
      }
    }
}

extern "C" void kernel_launch(void* const* d_in, const int* in_sizes, int n_in,
                              void* d_out, int out_size, void* d_ws, size_t ws_size,
                              hipStream_t stream) {
  const float* v    = (const float*)d_in[0];
  const float* p0   = (const float*)d_in[1];
  const float* Wenc = (const float*)d_in[2];
  const float* Wih  = (const float*)d_in[3];
  const float* Whh  = (const float*)d_in[4];
  const float* Wdec = (const float*)d_in[5];
  const float* bdec = (const float*)d_in[6];
  float* out = (float*)d_out;

  uint8_t* ws = (uint8_t*)d_ws;
  uint16_t* WhS = (uint16_t*)(ws);                 // fallback only
  uint16_t* WdS = (uint16_t*)(ws + 33554432);
  uint16_t* H0S = (uint16_t*)(ws + 37748736);
  uint16_t* Gsw = (uint16_t*)(ws + 38797312);
  float*    Part = (float*)(ws + 143654912);
  int*      flags = (int*)(ws + 160432128);

  cvt_wdec_kernel<<<512, 512, 0, stream>>>(Wdec, WdS, flags);
  enc_kernel<<<256, 512, 0, stream>>>(p0, Wenc, H0S);

  // persistent flag-synced RNN loop (cooperative launch for residency guarantee)
  const float* Whh_c = Whh;
  const uint16_t* H0S_c = H0S;
  void* args[7] = {(void*)&Whh_c, (void*)&H0S_c, (void*)&Gsw, (void*)&Part,
                   (void*)&v, (void*)&Wih, (void*)&flags};
  hipError_t e = hipLaunchCooperativeKernel(rnn_loop_kernel, dim3(256), dim3(512), args,
                                            (unsigned int)131072, stream);
  if (e != hipSuccess) {
    // fallback: per-step launches (round-1 path, ~1.96 ms class)
    (void)hipGetLastError();
    cvt_whh_kernel<<<4096, 512, 0, stream>>>(Whh, WhS);
    for (int t = 0; t < kT; t++) {
      const uint16_t* Asrc = (t == 0) ? H0S : (Gsw + (size_t)(t - 1) * 524288);
      stepmm_kernel<<<256, 512, 0, stream>>>(Asrc, WhS, Part);
      steptanh_kernel<<<256, 256, 0, stream>>>(Part, v, Wih, Gsw + (size_t)t * 524288, t);
    }
  }

  dec_kernel<<<416, 512, 0, stream>>>(Gsw, WdS, bdec, out);
}